// Round 1
// baseline (409.061 us; speedup 1.0000x reference)
//
#include <hip/hip_runtime.h>

typedef __attribute__((ext_vector_type(8))) short short8;
typedef __attribute__((ext_vector_type(4))) float f32x4;
typedef __attribute__((ext_vector_type(4))) int i32x4;

#define NSEQ 4096
#define MSEQ 1024
#define HID  512
#define CTXD 768

static __device__ __forceinline__ unsigned short f2bf(float f) {
  union { float f; unsigned u; } v; v.f = f;
  return (unsigned short)((v.u + 0x7fffu + ((v.u >> 16) & 1u)) >> 16);
}

// ---------------- weight transpose: W[K][N] f32 -> WT[N][K] bf16 ----------------
__global__ void k_transpose(const float* __restrict__ W, unsigned short* __restrict__ WT,
                            int K, int N) {
  __shared__ float tile[32][33];
  int k0 = blockIdx.x * 32, n0 = blockIdx.y * 32;
  int tx = threadIdx.x, ty = threadIdx.y;
#pragma unroll
  for (int i = 0; i < 32; i += 8)
    tile[ty + i][tx] = W[(size_t)(k0 + ty + i) * N + n0 + tx];
  __syncthreads();
#pragma unroll
  for (int i = 0; i < 32; i += 8)
    WT[(size_t)(n0 + ty + i) * K + k0 + tx] = f2bf(tile[tx][ty + i]);
}

// ---------------- generic GEMM: C[M][N] = A[M][K] * BT[N][K]^T + bias (+res) ----
// 128x128 tile, BK=64, 256 threads (4 waves, 2x2), XOR-swizzled LDS (st ((row&7)<<4))
template<bool F32>
static __device__ __forceinline__ void stage_tile(const char* src, char* dstbase,
                                                  int base_row, int K, int kk,
                                                  int row_s, int c0, unsigned sws) {
  char* dst = dstbase + row_s * 128;
  if constexpr (F32) {
    const float* p = (const float*)src + (size_t)(base_row + row_s) * K + kk + c0;
    unsigned short tmp[32] __attribute__((aligned(16)));
#pragma unroll
    for (int i = 0; i < 8; i++) {
      f32x4 v = *(const f32x4*)(p + i * 4);
      tmp[i * 4 + 0] = f2bf(v[0]); tmp[i * 4 + 1] = f2bf(v[1]);
      tmp[i * 4 + 2] = f2bf(v[2]); tmp[i * 4 + 3] = f2bf(v[3]);
    }
#pragma unroll
    for (int i = 0; i < 4; i++)
      *(i32x4*)(dst + (((unsigned)(c0 * 2 + i * 16)) ^ sws)) = *(const i32x4*)(tmp + i * 8);
  } else {
    const unsigned short* p = (const unsigned short*)src + (size_t)(base_row + row_s) * K + kk + c0;
#pragma unroll
    for (int i = 0; i < 4; i++)
      *(i32x4*)(dst + (((unsigned)(c0 * 2 + i * 16)) ^ sws)) = *(const i32x4*)(p + i * 8);
  }
}

template<bool A_F32, bool B_F32, bool BIAS_ROW, bool RES, bool OUT_BF16>
__global__ __launch_bounds__(256, 4) void k_gemm(
    const void* __restrict__ Av, const void* __restrict__ Bv,
    const float* __restrict__ bias, const float* __restrict__ resv,
    void* __restrict__ Cv, int M, int N, int K,
    long sA, long sB, long sC, long sR) {
  __shared__ __align__(16) char lds[32768];
  char* As = lds;
  char* Bs = lds + 16384;
  const int t = threadIdx.x, lane = t & 63, wid = t >> 6;
  const int wr = wid >> 1, wc = wid & 1;
  const int m0 = blockIdx.x * 128, n0 = blockIdx.y * 128, z = blockIdx.z;

  const char* Ab = (const char*)Av + (size_t)z * sA * (A_F32 ? 4 : 2);
  const char* Bb = (const char*)Bv + (size_t)z * sB * (B_F32 ? 4 : 2);

  const f32x4 fz = {0.f, 0.f, 0.f, 0.f};
  f32x4 acc[4][4];
#pragma unroll
  for (int i = 0; i < 4; i++)
#pragma unroll
    for (int j = 0; j < 4; j++) acc[i][j] = fz;

  const int row_s = t >> 1, c0 = (t & 1) * 32;
  const unsigned sws = (unsigned)(row_s & 7) << 4;

  for (int kk = 0; kk < K; kk += 64) {
    stage_tile<A_F32>(Ab, As, m0, K, kk, row_s, c0, sws);
    stage_tile<B_F32>(Bb, Bs, n0, K, kk, row_s, c0, sws);
    __syncthreads();
#pragma unroll
    for (int ks = 0; ks < 2; ks++) {
      short8 af[4], bfr[4];
#pragma unroll
      for (int i = 0; i < 4; i++) {
        int r = wr * 64 + i * 16 + (lane & 15);
        af[i] = *(const short8*)(As + r * 128 +
                 (((unsigned)(ks * 64 + (lane >> 4) * 16)) ^ ((unsigned)(r & 7) << 4)));
      }
#pragma unroll
      for (int i = 0; i < 4; i++) {
        int r = wc * 64 + i * 16 + (lane & 15);
        bfr[i] = *(const short8*)(Bs + r * 128 +
                 (((unsigned)(ks * 64 + (lane >> 4) * 16)) ^ ((unsigned)(r & 7) << 4)));
      }
#pragma unroll
      for (int i = 0; i < 4; i++)
#pragma unroll
        for (int j = 0; j < 4; j++)
          acc[i][j] = __builtin_amdgcn_mfma_f32_16x16x32_bf16(af[i], bfr[j], acc[i][j], 0, 0, 0);
    }
    __syncthreads();
  }

  const float* res = RES ? (resv + (size_t)z * sR) : nullptr;
  char* Cb = (char*)Cv + (size_t)z * sC * (OUT_BF16 ? 2 : 4);
#pragma unroll
  for (int i = 0; i < 4; i++) {
#pragma unroll
    for (int jj = 0; jj < 4; jj++) {
      int row = m0 + wr * 64 + i * 16 + (lane >> 4) * 4 + jj;
#pragma unroll
      for (int j = 0; j < 4; j++) {
        int col = n0 + wc * 64 + j * 16 + (lane & 15);
        float v = acc[i][j][jj];
        v += BIAS_ROW ? bias[row] : bias[col];
        if (RES) v += res[(size_t)row * N + col];
        if (OUT_BF16) ((unsigned short*)Cb)[(size_t)row * N + col] = f2bf(v);
        else          ((float*)Cb)[(size_t)row * N + col] = v;
      }
    }
  }
}

// ---------------- fused attention ----------------
// per block: 32 Q rows, full M=1024. 8 waves: phase1 wave w owns S cols [w*128,+128);
// phase2 wave w owns O^T rows (e) [w*64,+64). S in regs, P^ in swizzled LDS,
// O^T -> LDS (bank-spread layout) -> coalesced bf16 [n][e] store.
#define OTIDX(e, n) (((e) >> 5) * 1057 + (n) * 33 + ((e) & 31))

__global__ __launch_bounds__(512, 4) void k_attn(
    const unsigned short* __restrict__ qb,   // [B*N][512] bf16
    const unsigned short* __restrict__ kb,   // [B*M][512] bf16
    const unsigned short* __restrict__ vT,   // [B][512][1024] bf16 (V^T)
    unsigned short* __restrict__ ctxb) {     // [B*N][512] bf16
  __shared__ __align__(16) char lds[69824];
  char* Qs = lds;                         // [32][1024B] swizzled   (phase 1)
  char* Ps = lds;                         // [32][2048B] swizzled   (phase 1end-2)
  float* Ot = (float*)lds;                // OTIDX layout, 67636 B  (epilogue)
  float* smaxb = (float*)(lds + 67648);   // [8][32]
  float* ssumb = (float*)(lds + 68672);   // [8][32]
  float* tsumb = (float*)(lds + 69696);   // [32]

  const int t = threadIdx.x, lane = t & 63, w = t >> 6;
  const int bid = blockIdx.x;
  const int b = bid & 7;                  // batch -> XCD affinity
  const int n0 = (bid >> 3) * 32;
  const float scale = 0.044194173824159216f;  // 512^-0.5
  const f32x4 fz = {0.f, 0.f, 0.f, 0.f};

  // ---- load Q tile (32 rows x 512 bf16), swizzled into LDS
  {
    const char* qsrc = (const char*)(qb + ((size_t)b * NSEQ + n0) * HID);
#pragma unroll
    for (int i = 0; i < 4; i++) {
      int byteoff = t * 16 + i * 8192;
      int row = byteoff >> 10, o = byteoff & 1023;
      i32x4 v = *(const i32x4*)(qsrc + (size_t)row * 1024 + ((unsigned)o ^ ((unsigned)(row & 7) << 4)));
      *(i32x4*)(Qs + byteoff) = v;
    }
  }
  __syncthreads();

  // ---- phase 1: S[r][c] wave-tile = Q(32x512) @ K^T
  f32x4 s[2][8];
#pragma unroll
  for (int r = 0; r < 2; r++)
#pragma unroll
    for (int c = 0; c < 8; c++) s[r][c] = fz;

  const unsigned short* kbase = kb + (size_t)b * MSEQ * HID;
  for (int kk = 0; kk < HID; kk += 32) {
    short8 a[2];
#pragma unroll
    for (int r = 0; r < 2; r++) {
      int qr = r * 16 + (lane & 15);
      a[r] = *(const short8*)(Qs + qr * 1024 +
              (((unsigned)(kk * 2 + (lane >> 4) * 16)) ^ ((unsigned)(qr & 7) << 4)));
    }
#pragma unroll
    for (int c = 0; c < 8; c++) {
      int mr = w * 128 + c * 16 + (lane & 15);
      short8 bf = *(const short8*)(kbase + (size_t)mr * HID + kk + (lane >> 4) * 8);
      s[0][c] = __builtin_amdgcn_mfma_f32_16x16x32_bf16(a[0], bf, s[0][c], 0, 0, 0);
      s[1][c] = __builtin_amdgcn_mfma_f32_16x16x32_bf16(a[1], bf, s[1][c], 0, 0, 0);
    }
  }

  // ---- softmax (full row, cross-wave via LDS)
  float rmax[2][4], rsum[2][4], mfin[2][4];
#pragma unroll
  for (int r = 0; r < 2; r++)
#pragma unroll
    for (int jj = 0; jj < 4; jj++) {
      float m = -3e38f;
#pragma unroll
      for (int c = 0; c < 8; c++) m = fmaxf(m, s[r][c][jj] * scale);
      rmax[r][jj] = m;
    }
#pragma unroll
  for (int d = 1; d < 16; d <<= 1)
#pragma unroll
    for (int r = 0; r < 2; r++)
#pragma unroll
      for (int jj = 0; jj < 4; jj++)
        rmax[r][jj] = fmaxf(rmax[r][jj], __shfl_xor(rmax[r][jj], d, 64));
  if ((lane & 15) == 0) {
#pragma unroll
    for (int r = 0; r < 2; r++)
#pragma unroll
      for (int jj = 0; jj < 4; jj++)
        smaxb[w * 32 + r * 16 + (lane >> 4) * 4 + jj] = rmax[r][jj];
  }
  __syncthreads();                 // #2 : all waves done with Q & partial maxes
#pragma unroll
  for (int r = 0; r < 2; r++)
#pragma unroll
    for (int jj = 0; jj < 4; jj++) {
      float mm = -3e38f;
#pragma unroll
      for (int ww = 0; ww < 8; ww++)
        mm = fmaxf(mm, smaxb[ww * 32 + r * 16 + (lane >> 4) * 4 + jj]);
      mfin[r][jj] = mm;
      rsum[r][jj] = 0.f;
    }
  // exp, accumulate row-sums, write P^ (bf16, swizzled) -- overwrites Q (safe post-#2)
#pragma unroll
  for (int r = 0; r < 2; r++)
#pragma unroll
    for (int c = 0; c < 8; c++)
#pragma unroll
      for (int jj = 0; jj < 4; jj++) {
        float p = __expf(s[r][c][jj] * scale - mfin[r][jj]);
        rsum[r][jj] += p;
        int n = r * 16 + (lane >> 4) * 4 + jj;
        int m = w * 128 + c * 16 + (lane & 15);
        *(unsigned short*)(Ps + n * 2048 + (((unsigned)(m * 2)) ^ ((unsigned)(n & 7) << 4))) = f2bf(p);
      }
#pragma unroll
  for (int d = 1; d < 16; d <<= 1)
#pragma unroll
    for (int r = 0; r < 2; r++)
#pragma unroll
      for (int jj = 0; jj < 4; jj++)
        rsum[r][jj] += __shfl_xor(rsum[r][jj], d, 64);
  if ((lane & 15) == 0) {
#pragma unroll
    for (int r = 0; r < 2; r++)
#pragma unroll
      for (int jj = 0; jj < 4; jj++)
        ssumb[w * 32 + r * 16 + (lane >> 4) * 4 + jj] = rsum[r][jj];
  }
  __syncthreads();                 // #3 : P^ complete, partial sums complete
  if (w == 0 && lane < 32) {
    float sum = 0.f;
#pragma unroll
    for (int ww = 0; ww < 8; ww++) sum += ssumb[ww * 32 + lane];
    tsumb[lane] = sum;
  }

  // ---- phase 2: O^T = V^T @ P^T  (wave w: e in [w*64, w*64+64))
  f32x4 o[4][2];
#pragma unroll
  for (int fe = 0; fe < 4; fe++)
#pragma unroll
    for (int fn = 0; fn < 2; fn++) o[fe][fn] = fz;
  const unsigned short* vbase = vT + (size_t)b * HID * MSEQ;
  const int e00 = w * 64;
  for (int m0 = 0; m0 < MSEQ; m0 += 32) {
    short8 av[4];
#pragma unroll
    for (int fe = 0; fe < 4; fe++) {
      int e = e00 + fe * 16 + (lane & 15);
      av[fe] = *(const short8*)(vbase + (size_t)e * MSEQ + m0 + (lane >> 4) * 8);
    }
#pragma unroll
    for (int fn = 0; fn < 2; fn++) {
      int n = fn * 16 + (lane & 15);
      short8 pf = *(const short8*)(Ps + n * 2048 +
                  (((unsigned)((m0 + (lane >> 4) * 8) * 2)) ^ ((unsigned)(n & 7) << 4)));
#pragma unroll
      for (int fe = 0; fe < 4; fe++)
        o[fe][fn] = __builtin_amdgcn_mfma_f32_16x16x32_bf16(av[fe], pf, o[fe][fn], 0, 0, 0);
    }
  }
  __syncthreads();                 // #4 : P dead, tsumb visible

  float inv[2];
#pragma unroll
  for (int fn = 0; fn < 2; fn++) inv[fn] = 1.0f / tsumb[fn * 16 + (lane & 15)];
#pragma unroll
  for (int fe = 0; fe < 4; fe++)
#pragma unroll
    for (int fn = 0; fn < 2; fn++)
#pragma unroll
      for (int jj = 0; jj < 4; jj++) {
        int e = e00 + fe * 16 + (lane >> 4) * 4 + jj;
        int n = fn * 16 + (lane & 15);
        Ot[OTIDX(e, n)] = o[fe][fn][jj] * inv[fn];
      }
  __syncthreads();                 // #5

  {
    unsigned short* cdst = ctxb + ((size_t)b * NSEQ + n0) * HID;
    int n = t >> 4, e0t = (t & 15) * 32;
    unsigned short tmp[32] __attribute__((aligned(16)));
#pragma unroll
    for (int i = 0; i < 32; i++) tmp[i] = f2bf(Ot[OTIDX(e0t + i, n)]);
#pragma unroll
    for (int i = 0; i < 4; i++)
      *(i32x4*)(cdst + (size_t)n * HID + e0t + i * 8) = *(const i32x4*)(tmp + i * 8);
  }
}

// ---------------- launch ----------------
extern "C" void kernel_launch(void* const* d_in, const int* in_sizes, int n_in,
                              void* d_out, int out_size, void* d_ws, size_t ws_size,
                              hipStream_t stream) {
  (void)in_sizes; (void)n_in; (void)out_size; (void)ws_size;
  const float* x   = (const float*)d_in[0];
  const float* ctx = (const float*)d_in[1];
  const float* Wq  = (const float*)d_in[2];
  const float* bq  = (const float*)d_in[3];
  const float* Wk  = (const float*)d_in[4];
  const float* bk  = (const float*)d_in[5];
  const float* Wv  = (const float*)d_in[6];
  const float* bv  = (const float*)d_in[7];
  const float* Wo  = (const float*)d_in[8];
  const float* bo  = (const float*)d_in[9];
  float* out = (float*)d_out;

  char* ws = (char*)d_ws;
  unsigned short* qb   = (unsigned short*)(ws);              // 32768*512*2 = 33,554,432
  unsigned short* kbuf = (unsigned short*)(ws + 33554432);   // 8192*512*2  =  8,388,608
  unsigned short* vT   = (unsigned short*)(ws + 41943040);   // 8*512*1024*2 = 8,388,608
  unsigned short* ctxb = (unsigned short*)(ws + 50331648);   // 33,554,432
  unsigned short* WqT  = (unsigned short*)(ws + 83886080);   // 524,288
  unsigned short* WkT  = (unsigned short*)(ws + 84410368);   // 786,432
  unsigned short* WvT  = (unsigned short*)(ws + 85196800);   // 786,432
  unsigned short* WoT  = (unsigned short*)(ws + 85983232);   // 524,288  (end 86,507,520)

  dim3 tb(32, 8);
  k_transpose<<<dim3(16, 16), tb, 0, stream>>>(Wq, WqT, 512, 512);
  k_transpose<<<dim3(24, 16), tb, 0, stream>>>(Wk, WkT, 768, 512);
  k_transpose<<<dim3(24, 16), tb, 0, stream>>>(Wv, WvT, 768, 512);
  k_transpose<<<dim3(16, 16), tb, 0, stream>>>(Wo, WoT, 512, 512);

  // q = x @ Wq + bq              -> bf16 [32768][512]
  k_gemm<true, false, false, false, true><<<dim3(256, 4, 1), 256, 0, stream>>>(
      x, WqT, bq, nullptr, qb, 32768, 512, 512, 0, 0, 0, 0);
  // k = ctx @ Wk + bk            -> bf16 [8192][512]
  k_gemm<true, false, false, false, true><<<dim3(64, 4, 1), 256, 0, stream>>>(
      ctx, WkT, bk, nullptr, kbuf, 8192, 512, 768, 0, 0, 0, 0);
  // vT[b] = (ctx[b] @ Wv + bv)^T -> bf16 [8][512][1024]  (A=WvT, BT=ctx[b], bias per-row)
  k_gemm<false, true, true, false, true><<<dim3(4, 8, 8), 256, 0, stream>>>(
      WvT, ctx, bv, nullptr, vT, 512, 1024, 768, 0, (long)1024 * 768, (long)512 * 1024, 0);
  // attention: softmax(q k^T * scale) v  -> bf16 [32768][512]
  k_attn<<<dim3(1024), 512, 0, stream>>>(qb, kbuf, vT, ctxb);
  // out = ctx_out @ Wo + bo + x  -> f32
  k_gemm<false, false, false, true, false><<<dim3(256, 4, 1), 256, 0, stream>>>(
      ctxb, WoT, bo, x, out, 32768, 512, 512, 0, 0, 0, 0);
}

// Round 2
// 237.076 us; speedup vs baseline: 1.7254x; 1.7254x over previous
//
#include <hip/hip_runtime.h>

typedef __attribute__((ext_vector_type(8))) short short8;
typedef __attribute__((ext_vector_type(4))) float f32x4;
typedef __attribute__((ext_vector_type(4))) int i32x4;

#define NSEQ 4096
#define MSEQ 1024
#define HID  512
#define CTXD 768

static __device__ __forceinline__ unsigned short f2bf(float f) {
  union { float f; unsigned u; } v; v.f = f;
  return (unsigned short)((v.u + 0x7fffu + ((v.u >> 16) & 1u)) >> 16);
}

static __device__ __forceinline__ void gld16(const void* g, void* l) {
  __builtin_amdgcn_global_load_lds((const __attribute__((address_space(1))) void*)g,
                                   (__attribute__((address_space(3))) void*)l, 16, 0, 0);
}
static __device__ __forceinline__ void gld4(const void* g, void* l) {
  __builtin_amdgcn_global_load_lds((const __attribute__((address_space(1))) void*)g,
                                   (__attribute__((address_space(3))) void*)l, 4, 0, 0);
}

// ---------------- weight transpose: W[K][N] f32 -> WT[N][K] bf16 ----------------
__global__ void k_transpose(const float* __restrict__ W, unsigned short* __restrict__ WT,
                            int K, int N) {
  __shared__ float tile[32][33];
  int k0 = blockIdx.x * 32, n0 = blockIdx.y * 32;
  int tx = threadIdx.x, ty = threadIdx.y;
#pragma unroll
  for (int i = 0; i < 32; i += 8)
    tile[ty + i][tx] = W[(size_t)(k0 + ty + i) * N + n0 + tx];
  __syncthreads();
#pragma unroll
  for (int i = 0; i < 32; i += 8)
    WT[(size_t)(n0 + ty + i) * K + k0 + tx] = f2bf(tile[tx][ty + i]);
}

// ---------------- f32 -> bf16 cast, vectorized ----------------
__global__ void k_cast(const float* __restrict__ in, unsigned short* __restrict__ out, int n8) {
  int i = blockIdx.x * blockDim.x + threadIdx.x;
  int stride = gridDim.x * blockDim.x;
  for (; i < n8; i += stride) {
    f32x4 v0 = *(const f32x4*)(in + (size_t)i * 8);
    f32x4 v1 = *(const f32x4*)(in + (size_t)i * 8 + 4);
    unsigned short tmp[8] __attribute__((aligned(16)));
    tmp[0] = f2bf(v0[0]); tmp[1] = f2bf(v0[1]); tmp[2] = f2bf(v0[2]); tmp[3] = f2bf(v0[3]);
    tmp[4] = f2bf(v1[0]); tmp[5] = f2bf(v1[1]); tmp[6] = f2bf(v1[2]); tmp[7] = f2bf(v1[3]);
    *(i32x4*)(out + (size_t)i * 8) = *(const i32x4*)tmp;
  }
}

// ---------------- GEMM: C[M][N] = A[M][K](bf16) * BT[N][K](bf16)^T ----------------
// 128x128 tile, BK=64, 4 waves (2x2). global_load_lds staging (linear LDS dest,
// inverse-swizzled global source), double-buffered, counted vmcnt, raw s_barrier.
// BIAS_MODE: 0 none, 1 per-col, 2 per-row.
template<int BIAS_MODE, bool RES, bool OUT_BF16>
__global__ __launch_bounds__(256, 2) void k_gemm(
    const unsigned short* __restrict__ A, const unsigned short* __restrict__ B,
    const float* __restrict__ bias, const float* __restrict__ resv,
    void* __restrict__ Cv, int M, int N, int K,
    long sA, long sB, long sC, long sR) {
  __shared__ __align__(16) char lds[65536];  // 2 bufs x (A 16K + B 16K)
  const int t = threadIdx.x, lane = t & 63, wid = t >> 6;
  const int wr = wid >> 1, wc = wid & 1;
  const int m0 = blockIdx.x * 128, n0 = blockIdx.y * 128, z = blockIdx.z;
  const unsigned short* Ab = A + (size_t)z * sA;
  const unsigned short* Bb = B + (size_t)z * sB;

  const f32x4 fz = {0.f, 0.f, 0.f, 0.f};
  f32x4 acc[4][4];
#pragma unroll
  for (int i = 0; i < 4; i++)
#pragma unroll
    for (int j = 0; j < 4; j++) acc[i][j] = fz;

  const int srow = t >> 3;      // 0..31 (+32 per issue)
  const int schunk = t & 7;

  auto stage = [&](int kk, int buf) {
    const char* a8 = (const char*)Ab;
    const char* b8 = (const char*)Bb;
#pragma unroll
    for (int i = 0; i < 4; i++) {
      int row = i * 32 + srow;
      gld16(a8 + ((size_t)(m0 + row) * K + kk) * 2 + ((schunk ^ (row & 7)) << 4),
            lds + buf * 32768 + i * 4096 + wid * 1024);
    }
#pragma unroll
    for (int i = 0; i < 4; i++) {
      int row = i * 32 + srow;
      gld16(b8 + ((size_t)(n0 + row) * K + kk) * 2 + ((schunk ^ (row & 7)) << 4),
            lds + buf * 32768 + 16384 + i * 4096 + wid * 1024);
    }
  };

  stage(0, 0);
  int buf = 0;
  for (int kk = 0; kk < K; kk += 64) {
    if (kk + 64 < K) {
      stage(kk + 64, buf ^ 1);
      asm volatile("s_waitcnt vmcnt(8)" ::: "memory");
    } else {
      asm volatile("s_waitcnt vmcnt(0)" ::: "memory");
    }
    __builtin_amdgcn_s_barrier();
    const char* As = lds + buf * 32768;
    const char* Bs = As + 16384;
#pragma unroll
    for (int ks = 0; ks < 2; ks++) {
      short8 af[4], bfr[4];
#pragma unroll
      for (int i = 0; i < 4; i++) {
        int r = wr * 64 + i * 16 + (lane & 15);
        af[i] = *(const short8*)(As + r * 128 +
                 (((unsigned)(ks * 64 + (lane >> 4) * 16)) ^ ((unsigned)(r & 7) << 4)));
      }
#pragma unroll
      for (int i = 0; i < 4; i++) {
        int r = wc * 64 + i * 16 + (lane & 15);
        bfr[i] = *(const short8*)(Bs + r * 128 +
                 (((unsigned)(ks * 64 + (lane >> 4) * 16)) ^ ((unsigned)(r & 7) << 4)));
      }
#pragma unroll
      for (int i = 0; i < 4; i++)
#pragma unroll
        for (int j = 0; j < 4; j++)
          acc[i][j] = __builtin_amdgcn_mfma_f32_16x16x32_bf16(af[i], bfr[j], acc[i][j], 0, 0, 0);
    }
    asm volatile("s_waitcnt lgkmcnt(0)" ::: "memory");
    __builtin_amdgcn_s_barrier();
    buf ^= 1;
  }

  const float* res = RES ? (resv + (size_t)z * sR) : nullptr;
  char* Cb = (char*)Cv + (size_t)z * sC * (OUT_BF16 ? 2 : 4);
#pragma unroll
  for (int i = 0; i < 4; i++) {
#pragma unroll
    for (int jj = 0; jj < 4; jj++) {
      int row = m0 + wr * 64 + i * 16 + (lane >> 4) * 4 + jj;
#pragma unroll
      for (int j = 0; j < 4; j++) {
        int col = n0 + wc * 64 + j * 16 + (lane & 15);
        float v = acc[i][j][jj];
        if (BIAS_MODE == 1) v += bias[col];
        if (BIAS_MODE == 2) v += bias[row];
        if (RES) v += res[(size_t)row * N + col];
        if (OUT_BF16) ((unsigned short*)Cb)[(size_t)row * N + col] = f2bf(v);
        else          ((float*)Cb)[(size_t)row * N + col] = v;
      }
    }
  }
}

// ---------------- QK^T + softmax -> normalized P^ (bf16) ----------------
// Block: 64 q-rows x full M=1024, 8 waves. Wave w owns m-slice [w*128,+128).
// S (64x1024 f32) in registers: 128 VGPR/lane. K streamed as [1024][32-hid]
// chunks (64KB) + Q chunks [64][32] (4KB), double-buffered via global_load_lds.
__global__ __launch_bounds__(512, 1) void k_qks(
    const unsigned short* __restrict__ qb,   // [B*4096][512] bf16
    const unsigned short* __restrict__ kb,   // [B*1024][512] bf16
    unsigned short* __restrict__ phat) {     // [B][4096][1024] bf16 (normalized)
  __shared__ __align__(16) char lds[143616];
  char* Kb0 = lds;                         // [2][65536]
  char* Qb0 = lds + 131072;                // [2][4096]
  float* pmax = (float*)(lds + 139264);    // [8][64]
  float* psum = (float*)(lds + 141312);    // [8][64]
  float* gbuf = (float*)(lds + 143360);    // [64]

  const int t = threadIdx.x, lane = t & 63, w = t >> 6;
  const int g = lane >> 4, l15 = lane & 15;
  const int bid = blockIdx.x;
  const int b = bid & 7;                   // batch -> XCD affinity
  const int n0 = (bid >> 3) * 64;
  const char* qbase = (const char*)(qb + ((size_t)b * NSEQ + n0) * HID);
  const char* kbase = (const char*)(kb + (size_t)b * MSEQ * HID);

  auto stage = [&](int ks2, int buf) {
#pragma unroll
    for (int i = 0; i < 8; i++) {
      int row = i * 128 + (t >> 2);
      int c = t & 3;
      gld16(kbase + ((size_t)row * HID + ks2 * 32) * 2 + ((c ^ ((row >> 1) & 3)) << 4),
            Kb0 + buf * 65536 + i * 8192 + w * 1024);
    }
#pragma unroll
    for (int j = 0; j < 2; j++) {
      int row = j * 32 + (t >> 4);
      int o = (t & 15) * 4;
      gld4(qbase + ((size_t)row * HID + ks2 * 32) * 2 +
               ((((o >> 4) ^ ((row >> 1) & 3)) << 4) | (o & 15)),
           Qb0 + buf * 4096 + j * 2048 + w * 256);
    }
  };

  const f32x4 fz = {0.f, 0.f, 0.f, 0.f};
  f32x4 s[4][8];
#pragma unroll
  for (int qf = 0; qf < 4; qf++)
#pragma unroll
    for (int mf = 0; mf < 8; mf++) s[qf][mf] = fz;

  stage(0, 0);
  int buf = 0;
  for (int ks2 = 0; ks2 < 16; ks2++) {
    if (ks2 < 15) {
      stage(ks2 + 1, buf ^ 1);
      asm volatile("s_waitcnt vmcnt(10)" ::: "memory");
    } else {
      asm volatile("s_waitcnt vmcnt(0)" ::: "memory");
    }
    __builtin_amdgcn_s_barrier();
    const char* Kc = Kb0 + buf * 65536;
    const char* Qc = Qb0 + buf * 4096;
    short8 aq[4], bk[8];
#pragma unroll
    for (int qf = 0; qf < 4; qf++) {
      int q = qf * 16 + l15;
      aq[qf] = *(const short8*)(Qc + q * 64 + ((g * 16) ^ (((q >> 1) & 3) << 4)));
    }
#pragma unroll
    for (int mf = 0; mf < 8; mf++) {
      int m = w * 128 + mf * 16 + l15;
      bk[mf] = *(const short8*)(Kc + m * 64 + ((g * 16) ^ (((m >> 1) & 3) << 4)));
    }
#pragma unroll
    for (int qf = 0; qf < 4; qf++)
#pragma unroll
      for (int mf = 0; mf < 8; mf++)
        s[qf][mf] = __builtin_amdgcn_mfma_f32_16x16x32_bf16(aq[qf], bk[mf], s[qf][mf], 0, 0, 0);
    asm volatile("s_waitcnt lgkmcnt(0)" ::: "memory");
    __builtin_amdgcn_s_barrier();
    buf ^= 1;
  }

  // ---- softmax (exact, full row) ----
  const float scale = 0.044194173824159216f;  // 512^-0.5
#pragma unroll
  for (int qf = 0; qf < 4; qf++)
#pragma unroll
    for (int mf = 0; mf < 8; mf++)
#pragma unroll
      for (int jj = 0; jj < 4; jj++) s[qf][mf][jj] *= scale;

  float rmax[4][4];
#pragma unroll
  for (int qf = 0; qf < 4; qf++)
#pragma unroll
    for (int jj = 0; jj < 4; jj++) {
      float m = s[qf][0][jj];
#pragma unroll
      for (int mf = 1; mf < 8; mf++) m = fmaxf(m, s[qf][mf][jj]);
      rmax[qf][jj] = m;
    }
#pragma unroll
  for (int d = 1; d < 16; d <<= 1)
#pragma unroll
    for (int qf = 0; qf < 4; qf++)
#pragma unroll
      for (int jj = 0; jj < 4; jj++)
        rmax[qf][jj] = fmaxf(rmax[qf][jj], __shfl_xor(rmax[qf][jj], d, 64));
  if (l15 == 0) {
#pragma unroll
    for (int qf = 0; qf < 4; qf++)
#pragma unroll
      for (int jj = 0; jj < 4; jj++)
        pmax[w * 64 + qf * 16 + g * 4 + jj] = rmax[qf][jj];
  }
  __syncthreads();
  if (t < 64) {
    float m = pmax[t];
#pragma unroll
    for (int ww = 1; ww < 8; ww++) m = fmaxf(m, pmax[ww * 64 + t]);
    gbuf[t] = m;
  }
  __syncthreads();
  float fm[4][4], rs[4][4];
#pragma unroll
  for (int qf = 0; qf < 4; qf++)
#pragma unroll
    for (int jj = 0; jj < 4; jj++) {
      fm[qf][jj] = gbuf[qf * 16 + g * 4 + jj];
      rs[qf][jj] = 0.f;
    }
#pragma unroll
  for (int qf = 0; qf < 4; qf++)
#pragma unroll
    for (int mf = 0; mf < 8; mf++)
#pragma unroll
      for (int jj = 0; jj < 4; jj++) {
        float p = __expf(s[qf][mf][jj] - fm[qf][jj]);
        s[qf][mf][jj] = p;
        rs[qf][jj] += p;
      }
#pragma unroll
  for (int d = 1; d < 16; d <<= 1)
#pragma unroll
    for (int qf = 0; qf < 4; qf++)
#pragma unroll
      for (int jj = 0; jj < 4; jj++)
        rs[qf][jj] += __shfl_xor(rs[qf][jj], d, 64);
  __syncthreads();   // pmax reads done; reuse-safe for psum writes
  if (l15 == 0) {
#pragma unroll
    for (int qf = 0; qf < 4; qf++)
#pragma unroll
      for (int jj = 0; jj < 4; jj++)
        psum[w * 64 + qf * 16 + g * 4 + jj] = rs[qf][jj];
  }
  __syncthreads();
  if (t < 64) {
    float ssum = psum[t];
#pragma unroll
    for (int ww = 1; ww < 8; ww++) ssum += psum[ww * 64 + t];
    gbuf[t] = 1.0f / ssum;
  }
  __syncthreads();
  unsigned short* pb = phat + (size_t)b * NSEQ * MSEQ;
#pragma unroll
  for (int qf = 0; qf < 4; qf++)
#pragma unroll
    for (int jj = 0; jj < 4; jj++) {
      float fi = gbuf[qf * 16 + g * 4 + jj];
      int row = n0 + qf * 16 + g * 4 + jj;
      unsigned short* pr = pb + (size_t)row * MSEQ + w * 128 + l15;
#pragma unroll
      for (int mf = 0; mf < 8; mf++)
        pr[mf * 16] = f2bf(s[qf][mf][jj] * fi);
    }
}

// ---------------- launch ----------------
extern "C" void kernel_launch(void* const* d_in, const int* in_sizes, int n_in,
                              void* d_out, int out_size, void* d_ws, size_t ws_size,
                              hipStream_t stream) {
  (void)in_sizes; (void)n_in; (void)out_size; (void)ws_size;
  const float* x   = (const float*)d_in[0];
  const float* ctx = (const float*)d_in[1];
  const float* Wq  = (const float*)d_in[2];
  const float* bq  = (const float*)d_in[3];
  const float* Wk  = (const float*)d_in[4];
  const float* bk  = (const float*)d_in[5];
  const float* Wv  = (const float*)d_in[6];
  const float* bv  = (const float*)d_in[7];
  const float* Wo  = (const float*)d_in[8];
  const float* bo  = (const float*)d_in[9];
  float* out = (float*)d_out;

  char* ws = (char*)d_ws;
  unsigned short* qb   = (unsigned short*)(ws);              // 33,554,432
  unsigned short* kbuf = (unsigned short*)(ws + 33554432);   //  8,388,608
  unsigned short* vT   = (unsigned short*)(ws + 41943040);   //  8,388,608
  unsigned short* ctxb = (unsigned short*)(ws + 50331648);   // 33,554,432
  unsigned short* WqT  = (unsigned short*)(ws + 83886080);   //    524,288
  unsigned short* WkT  = (unsigned short*)(ws + 84410368);   //    786,432
  unsigned short* WvT  = (unsigned short*)(ws + 85196800);   //    786,432
  unsigned short* WoT  = (unsigned short*)(ws + 85983232);   //    524,288 -> 86,507,520
  // phat overlays xb+cb (both dead before k_qks runs)
  unsigned short* phat = (unsigned short*)(ws + 86507520);   // 67,108,864 -> 153,616,384
  unsigned short* xb   = (unsigned short*)(ws + 86507520);   // 33,554,432 (dead after q-GEMM)
  unsigned short* cb   = (unsigned short*)(ws + 120061952);  // 12,582,912 (dead after k/v-GEMM)

  dim3 tb(32, 8);
  k_transpose<<<dim3(16, 16), tb, 0, stream>>>(Wq, WqT, 512, 512);
  k_transpose<<<dim3(24, 16), tb, 0, stream>>>(Wk, WkT, 768, 512);
  k_transpose<<<dim3(24, 16), tb, 0, stream>>>(Wv, WvT, 768, 512);
  k_transpose<<<dim3(16, 16), tb, 0, stream>>>(Wo, WoT, 512, 512);

  k_cast<<<dim3(2048), 256, 0, stream>>>(x,   xb, 2097152);  // 8*4096*512/8
  k_cast<<<dim3(2048), 256, 0, stream>>>(ctx, cb,  786432);  // 8*1024*768/8

  // q = x @ Wq + bq -> bf16 [32768][512]
  k_gemm<1, false, true><<<dim3(256, 4, 1), 256, 0, stream>>>(
      xb, WqT, bq, nullptr, qb, 32768, 512, 512, 0, 0, 0, 0);
  // k = ctx @ Wk + bk -> bf16 [8192][512]
  k_gemm<1, false, true><<<dim3(64, 4, 1), 256, 0, stream>>>(
      cb, WkT, bk, nullptr, kbuf, 8192, 512, 768, 0, 0, 0, 0);
  // vT[b] = (ctx[b] @ Wv + bv)^T -> bf16 [8][512][1024]
  k_gemm<2, false, true><<<dim3(4, 8, 8), 256, 0, stream>>>(
      WvT, cb, bv, nullptr, vT, 512, 1024, 768, 0, (long)1024 * 768, (long)512 * 1024, 0);
  // P^ = softmax(q k^T * scale), normalized -> bf16 [8][4096][1024]
  k_qks<<<dim3(512), 512, 0, stream>>>(qb, kbuf, phat);
  // ctx_out[b] = P^[b] @ vT[b]^T -> bf16 [8][4096][512]
  k_gemm<0, false, true><<<dim3(32, 4, 8), 256, 0, stream>>>(
      phat, vT, nullptr, nullptr, ctxb, 4096, 512, 1024,
      (long)4096 * 1024, (long)512 * 1024, (long)4096 * 512, 0);
  // out = ctx_out @ Wo + bo + x -> f32
  k_gemm<1, true, false><<<dim3(256, 4, 1), 256, 0, stream>>>(
      ctxb, WoT, bo, x, out, 32768, 512, 512, 0, 0, 0, 0);
}